// Round 1
// baseline (3216.026 us; speedup 1.0000x reference)
//
#include <hip/hip_runtime.h>

#define USER_COUNT 100000
#define ITEM_COUNT 50000
#define N_NODES    150000   // USER_COUNT + ITEM_COUNT
#define EMB        64
#define N_EDGES    1250000
#define BATCH      4096
#define GCN_LAYERS 3

// ---------------------------------------------------------------------------
// x0 = concat(user_emb, item_emb), vectorized float4 copy
// ---------------------------------------------------------------------------
__global__ void k_init_concat(const float* __restrict__ ue,
                              const float* __restrict__ ie,
                              float* __restrict__ x) {
    const size_t nu4 = (size_t)USER_COUNT * EMB / 4;   // 1.6M float4
    const size_t nt4 = (size_t)N_NODES   * EMB / 4;    // 2.4M float4
    size_t i = (size_t)blockIdx.x * blockDim.x + threadIdx.x;
    if (i < nu4) {
        ((float4*)x)[i] = ((const float4*)ue)[i];
    } else if (i < nt4) {
        ((float4*)x)[i] = ((const float4*)ie)[i - nu4];
    }
}

// ---------------------------------------------------------------------------
// Scatter SpMM: for each edge e, x_new[row[e]] += w[e] * x_old[col[e]]
// 16 threads per edge, each handling 4 dims via float4 load + 4 atomics.
// ---------------------------------------------------------------------------
__global__ void k_scatter(const int* __restrict__ row,
                          const int* __restrict__ col,
                          const float* __restrict__ w,
                          const float* __restrict__ xin,
                          float* __restrict__ xout) {
    int t = blockIdx.x * blockDim.x + threadIdx.x;
    int e = t >> 4;           // edge index
    int l = t & 15;           // 16 lanes per edge; lane l -> dims [4l, 4l+4)
    if (e >= N_EDGES) return;
    int   r  = row[e];
    int   c  = col[e];
    float ww = w[e];
    float4 v = ((const float4*)(xin + (size_t)c * EMB))[l];
    float* dst = xout + (size_t)r * EMB + l * 4;
    atomicAdd(dst + 0, ww * v.x);
    atomicAdd(dst + 1, ww * v.y);
    atomicAdd(dst + 2, ww * v.z);
    atomicAdd(dst + 3, ww * v.w);
}

// ---------------------------------------------------------------------------
// Gather-accumulate: out[b] += scale * x[idx[b] + base]
// 16 threads per batch row, float4.
// ---------------------------------------------------------------------------
__global__ void k_gather_add(const int* __restrict__ idx, int base,
                             const float* __restrict__ x,
                             float* __restrict__ out, float scale) {
    int t = blockIdx.x * blockDim.x + threadIdx.x;
    int b = t >> 4;
    int l = t & 15;
    if (b >= BATCH) return;
    int node = idx[b] + base;
    float4 v = ((const float4*)(x + (size_t)node * EMB))[l];
    float4* o = (float4*)out + (size_t)b * (EMB / 4) + l;
    float4 cur = *o;
    cur.x += scale * v.x;
    cur.y += scale * v.y;
    cur.z += scale * v.z;
    cur.w += scale * v.w;
    *o = cur;
}

extern "C" void kernel_launch(void* const* d_in, const int* in_sizes, int n_in,
                              void* d_out, int out_size, void* d_ws, size_t ws_size,
                              hipStream_t stream) {
    const float* user_emb    = (const float*)d_in[0];
    const float* item_emb    = (const float*)d_in[1];
    const int*   edge_row    = (const int*)d_in[2];
    const int*   edge_col    = (const int*)d_in[3];
    const float* edge_weight = (const float*)d_in[4];
    const int*   users       = (const int*)d_in[5];
    const int*   items       = (const int*)d_in[6];
    float* out = (float*)d_out;

    const size_t node_floats = (size_t)N_NODES * EMB;   // 9.6M floats
    float* xa = (float*)d_ws;                           // ping
    float* xb = xa + node_floats;                       // pong

    const float scale = 1.0f / (GCN_LAYERS + 1);        // 0.25

    // x0 = ego = concat(user_emb, item_emb)
    {
        size_t n4 = node_floats / 4;
        int blocks = (int)((n4 + 255) / 256);
        k_init_concat<<<blocks, 256, 0, stream>>>(user_emb, item_emb, xa);
    }

    // out = 0, then += 0.25 * ego[sel]
    hipMemsetAsync(d_out, 0, (size_t)out_size * sizeof(float), stream);
    {
        int blocks = (BATCH * 16 + 255) / 256;
        k_gather_add<<<blocks, 256, 0, stream>>>(users, 0, xa, out, scale);
        k_gather_add<<<blocks, 256, 0, stream>>>(items, USER_COUNT, xa,
                                                 out + (size_t)BATCH * EMB, scale);
    }

    float* x_old = xa;
    float* x_new = xb;
    const int scatter_blocks = (int)(((size_t)N_EDGES * 16 + 255) / 256);
    const int gather_blocks  = (BATCH * 16 + 255) / 256;

    for (int layer = 0; layer < GCN_LAYERS; ++layer) {
        hipMemsetAsync(x_new, 0, node_floats * sizeof(float), stream);
        k_scatter<<<scatter_blocks, 256, 0, stream>>>(edge_row, edge_col, edge_weight,
                                                      x_old, x_new);
        k_gather_add<<<gather_blocks, 256, 0, stream>>>(users, 0, x_new, out, scale);
        k_gather_add<<<gather_blocks, 256, 0, stream>>>(items, USER_COUNT, x_new,
                                                        out + (size_t)BATCH * EMB, scale);
        // swap ping-pong
        float* tmp = x_old; x_old = x_new; x_new = tmp;
    }
}

// Round 2
// 437.939 us; speedup vs baseline: 7.3435x; 7.3435x over previous
//
#include <hip/hip_runtime.h>

#define USER_COUNT 100000
#define ITEM_COUNT 50000
#define N_NODES    150000   // USER_COUNT + ITEM_COUNT
#define EMB        64
#define N_EDGES    1250000
#define BATCH      4096
#define GCN_LAYERS 3

#define SCAN_CHUNK   1024                       // per scan block (256 thr x 4)
#define SCAN_BLOCKS  ((N_NODES + SCAN_CHUNK - 1) / SCAN_CHUNK)   // 147
#define NPAD         150016                     // padded int stride (16B mult)

// ---------------------------------------------------------------------------
// x0 = concat(user_emb, item_emb), vectorized float4 copy
// ---------------------------------------------------------------------------
__global__ void k_init_concat(const float* __restrict__ ue,
                              const float* __restrict__ ie,
                              float* __restrict__ x) {
    const size_t nu4 = (size_t)USER_COUNT * EMB / 4;
    const size_t nt4 = (size_t)N_NODES   * EMB / 4;
    size_t i = (size_t)blockIdx.x * blockDim.x + threadIdx.x;
    if (i < nu4) {
        ((float4*)x)[i] = ((const float4*)ue)[i];
    } else if (i < nt4) {
        ((float4*)x)[i] = ((const float4*)ie)[i - nu4];
    }
}

// ---------------------------------------------------------------------------
// CSR build: histogram of edge rows
// ---------------------------------------------------------------------------
__global__ void k_hist(const int* __restrict__ row, int* __restrict__ counts) {
    int e = blockIdx.x * blockDim.x + threadIdx.x;
    if (e < N_EDGES) atomicAdd(&counts[row[e]], 1);
}

// ---------------------------------------------------------------------------
// Exclusive scan, 3-kernel version. scan1: per-block local exclusive scan +
// block total. scan2: exclusive scan of block totals (single block).
// scan3: add block offset; also mirror into cursor[].
// ---------------------------------------------------------------------------
__global__ void k_scan1(const int* __restrict__ counts,
                        int* __restrict__ scanned,
                        int* __restrict__ part) {
    __shared__ int lds[256];
    int tid  = threadIdx.x;
    int base = blockIdx.x * SCAN_CHUNK + tid * 4;
    int v0 = (base + 0 < N_NODES) ? counts[base + 0] : 0;
    int v1 = (base + 1 < N_NODES) ? counts[base + 1] : 0;
    int v2 = (base + 2 < N_NODES) ? counts[base + 2] : 0;
    int v3 = (base + 3 < N_NODES) ? counts[base + 3] : 0;
    int tsum = v0 + v1 + v2 + v3;
    lds[tid] = tsum;
    __syncthreads();
    for (int off = 1; off < 256; off <<= 1) {
        int t = (tid >= off) ? lds[tid - off] : 0;
        __syncthreads();
        lds[tid] += t;
        __syncthreads();
    }
    if (tid == 255) part[blockIdx.x] = lds[255];
    int run = lds[tid] - tsum;   // exclusive
    if (base + 0 < N_NODES) scanned[base + 0] = run; run += v0;
    if (base + 1 < N_NODES) scanned[base + 1] = run; run += v1;
    if (base + 2 < N_NODES) scanned[base + 2] = run; run += v2;
    if (base + 3 < N_NODES) scanned[base + 3] = run;
}

__global__ void k_scan2(int* __restrict__ part, int* __restrict__ scanned) {
    __shared__ int lds[256];
    int tid = threadIdx.x;
    int v = (tid < SCAN_BLOCKS) ? part[tid] : 0;
    lds[tid] = v;
    __syncthreads();
    for (int off = 1; off < 256; off <<= 1) {
        int t = (tid >= off) ? lds[tid - off] : 0;
        __syncthreads();
        lds[tid] += t;
        __syncthreads();
    }
    if (tid < SCAN_BLOCKS) part[tid] = lds[tid] - v;  // exclusive
    if (tid == 0) scanned[N_NODES] = N_EDGES;         // total is a constant
}

__global__ void k_scan3(int* __restrict__ scanned,
                        const int* __restrict__ part,
                        int* __restrict__ cursor) {
    int off  = part[blockIdx.x];
    int base = blockIdx.x * SCAN_CHUNK + threadIdx.x * 4;
    #pragma unroll
    for (int j = 0; j < 4; ++j) {
        int i = base + j;
        if (i < N_NODES) {
            int v = scanned[i] + off;
            scanned[i] = v;
            cursor[i]  = v;
        }
    }
}

// ---------------------------------------------------------------------------
// CSR fill: edge_sorted[pos] = {col, w}, pos via per-row atomic cursor
// ---------------------------------------------------------------------------
__global__ void k_fill(const int* __restrict__ row, const int* __restrict__ col,
                       const float* __restrict__ w,
                       int* __restrict__ cursor, int2* __restrict__ edges) {
    int e = blockIdx.x * blockDim.x + threadIdx.x;
    if (e >= N_EDGES) return;
    int pos = atomicAdd(&cursor[row[e]], 1);
    int2 v;
    v.x = col[e];
    v.y = __float_as_int(w[e]);
    edges[pos] = v;
}

// ---------------------------------------------------------------------------
// Gather SpMM: one 64-lane wave per node, lane = dim.
// x_new[n][d] = sum_e w_e * x_old[col_e][d]
// ---------------------------------------------------------------------------
__global__ void k_spmm(const int* __restrict__ row_start,
                       const int2* __restrict__ edges,
                       const float* __restrict__ xin,
                       float* __restrict__ xout) {
    int n = blockIdx.x * 4 + (threadIdx.x >> 6);
    int d = threadIdx.x & 63;
    if (n >= N_NODES) return;
    int s = row_start[n];
    int e = row_start[n + 1];
    float acc0 = 0.0f, acc1 = 0.0f;
    int i = s;
    for (; i + 1 < e; i += 2) {
        int2 e0 = edges[i];
        int2 e1 = edges[i + 1];
        acc0 += __int_as_float(e0.y) * xin[(size_t)e0.x * EMB + d];
        acc1 += __int_as_float(e1.y) * xin[(size_t)e1.x * EMB + d];
    }
    if (i < e) {
        int2 e0 = edges[i];
        acc0 += __int_as_float(e0.y) * xin[(size_t)e0.x * EMB + d];
    }
    xout[(size_t)n * EMB + d] = acc0 + acc1;
}

// ---------------------------------------------------------------------------
// Fallback scatter (round-0 path, used only if ws too small for CSR)
// ---------------------------------------------------------------------------
__global__ void k_scatter(const int* __restrict__ row,
                          const int* __restrict__ col,
                          const float* __restrict__ w,
                          const float* __restrict__ xin,
                          float* __restrict__ xout) {
    int t = blockIdx.x * blockDim.x + threadIdx.x;
    int e = t >> 4;
    int l = t & 15;
    if (e >= N_EDGES) return;
    int   r  = row[e];
    int   c  = col[e];
    float ww = w[e];
    float4 v = ((const float4*)(xin + (size_t)c * EMB))[l];
    float* dst = xout + (size_t)r * EMB + l * 4;
    atomicAdd(dst + 0, ww * v.x);
    atomicAdd(dst + 1, ww * v.y);
    atomicAdd(dst + 2, ww * v.z);
    atomicAdd(dst + 3, ww * v.w);
}

// ---------------------------------------------------------------------------
// Gather-accumulate into output: out[b] += scale * x[idx[b] + base]
// ---------------------------------------------------------------------------
__global__ void k_gather_add(const int* __restrict__ idx, int base,
                             const float* __restrict__ x,
                             float* __restrict__ out, float scale) {
    int t = blockIdx.x * blockDim.x + threadIdx.x;
    int b = t >> 4;
    int l = t & 15;
    if (b >= BATCH) return;
    int node = idx[b] + base;
    float4 v = ((const float4*)(x + (size_t)node * EMB))[l];
    float4* o = (float4*)out + (size_t)b * (EMB / 4) + l;
    float4 cur = *o;
    cur.x += scale * v.x;
    cur.y += scale * v.y;
    cur.z += scale * v.z;
    cur.w += scale * v.w;
    *o = cur;
}

extern "C" void kernel_launch(void* const* d_in, const int* in_sizes, int n_in,
                              void* d_out, int out_size, void* d_ws, size_t ws_size,
                              hipStream_t stream) {
    const float* user_emb    = (const float*)d_in[0];
    const float* item_emb    = (const float*)d_in[1];
    const int*   edge_row    = (const int*)d_in[2];
    const int*   edge_col    = (const int*)d_in[3];
    const float* edge_weight = (const float*)d_in[4];
    const int*   users       = (const int*)d_in[5];
    const int*   items       = (const int*)d_in[6];
    float* out = (float*)d_out;

    const size_t node_floats = (size_t)N_NODES * EMB;   // 9.6M floats
    const float scale = 1.0f / (GCN_LAYERS + 1);        // 0.25

    // ws layout
    float* xa        = (float*)d_ws;
    float* xb        = xa + node_floats;
    int*   row_start = (int*)(xb + node_floats);        // NPAD ints (uses N_NODES+1)
    int*   cursor    = row_start + NPAD;
    int*   counts    = cursor + NPAD;
    int*   part      = counts + NPAD;                   // 256 ints
    int2*  edges     = (int2*)(part + 256);
    size_t need      = (size_t)((char*)(edges + N_EDGES) - (char*)d_ws);

    const int gather_blocks = (BATCH * 16 + 255) / 256;

    // x0 = ego = concat(user_emb, item_emb)
    {
        size_t n4 = node_floats / 4;
        int blocks = (int)((n4 + 255) / 256);
        k_init_concat<<<blocks, 256, 0, stream>>>(user_emb, item_emb, xa);
    }

    // out = 0.25 * ego[sel]
    hipMemsetAsync(d_out, 0, (size_t)out_size * sizeof(float), stream);
    k_gather_add<<<gather_blocks, 256, 0, stream>>>(users, 0, xa, out, scale);
    k_gather_add<<<gather_blocks, 256, 0, stream>>>(items, USER_COUNT, xa,
                                                    out + (size_t)BATCH * EMB, scale);

    if (ws_size >= need) {
        // ---------- CSR build ----------
        hipMemsetAsync(counts, 0, (size_t)NPAD * sizeof(int), stream);
        {
            int blocks = (N_EDGES + 255) / 256;
            k_hist<<<blocks, 256, 0, stream>>>(edge_row, counts);
        }
        k_scan1<<<SCAN_BLOCKS, 256, 0, stream>>>(counts, row_start, part);
        k_scan2<<<1, 256, 0, stream>>>(part, row_start);
        k_scan3<<<SCAN_BLOCKS, 256, 0, stream>>>(row_start, part, cursor);
        {
            int blocks = (N_EDGES + 255) / 256;
            k_fill<<<blocks, 256, 0, stream>>>(edge_row, edge_col, edge_weight,
                                               cursor, edges);
        }

        // ---------- 3 gather-SpMM layers ----------
        float* x_old = xa;
        float* x_new = xb;
        const int spmm_blocks = (N_NODES + 3) / 4;
        for (int layer = 0; layer < GCN_LAYERS; ++layer) {
            k_spmm<<<spmm_blocks, 256, 0, stream>>>(row_start, edges, x_old, x_new);
            k_gather_add<<<gather_blocks, 256, 0, stream>>>(users, 0, x_new, out, scale);
            k_gather_add<<<gather_blocks, 256, 0, stream>>>(items, USER_COUNT, x_new,
                                                            out + (size_t)BATCH * EMB, scale);
            float* tmp = x_old; x_old = x_new; x_new = tmp;
        }
    } else {
        // ---------- fallback: atomic scatter ----------
        float* x_old = xa;
        float* x_new = xb;
        const int scatter_blocks = (int)(((size_t)N_EDGES * 16 + 255) / 256);
        for (int layer = 0; layer < GCN_LAYERS; ++layer) {
            hipMemsetAsync(x_new, 0, node_floats * sizeof(float), stream);
            k_scatter<<<scatter_blocks, 256, 0, stream>>>(edge_row, edge_col, edge_weight,
                                                          x_old, x_new);
            k_gather_add<<<gather_blocks, 256, 0, stream>>>(users, 0, x_new, out, scale);
            k_gather_add<<<gather_blocks, 256, 0, stream>>>(items, USER_COUNT, x_new,
                                                            out + (size_t)BATCH * EMB, scale);
            float* tmp = x_old; x_old = x_new; x_new = tmp;
        }
    }
}

// Round 3
// 273.756 us; speedup vs baseline: 11.7478x; 1.5997x over previous
//
#include <hip/hip_runtime.h>

#define USER_COUNT 100000
#define ITEM_COUNT 50000
#define N_NODES    150000   // USER_COUNT + ITEM_COUNT
#define EMB        64
#define N_EDGES    1250000
#define BATCH      4096
#define GCN_LAYERS 3

#define SCAN_CHUNK   1024                       // per scan block (256 thr x 4)
#define SCAN_BLOCKS  ((N_NODES + SCAN_CHUNK - 1) / SCAN_CHUNK)   // 147
#define NPAD         150016                     // padded int stride (16B mult)

// bf16x2 pack/unpack (round-to-nearest-even; inputs are finite)
static __device__ __forceinline__ unsigned pack_bf16x2(float a, float b) {
    unsigned ua = __float_as_uint(a);
    unsigned ub = __float_as_uint(b);
    ua += 0x7FFFu + ((ua >> 16) & 1u);
    ub += 0x7FFFu + ((ub >> 16) & 1u);
    return (ua >> 16) | (ub & 0xFFFF0000u);
}
static __device__ __forceinline__ float2 unpack_bf16x2(unsigned v) {
    float2 r;
    r.x = __uint_as_float(v << 16);
    r.y = __uint_as_float(v & 0xFFFF0000u);
    return r;
}

// ---------------------------------------------------------------------------
// x0 = concat(user_emb, item_emb) converted to bf16x2-packed table
// ---------------------------------------------------------------------------
__global__ void k_concat_bf16(const float* __restrict__ ue,
                              const float* __restrict__ ie,
                              unsigned* __restrict__ x) {
    const size_t nu4 = (size_t)USER_COUNT * EMB / 4;
    const size_t nt4 = (size_t)N_NODES   * EMB / 4;
    size_t i = (size_t)blockIdx.x * blockDim.x + threadIdx.x;
    if (i >= nt4) return;
    float4 v = (i < nu4) ? ((const float4*)ue)[i] : ((const float4*)ie)[i - nu4];
    uint2 p;
    p.x = pack_bf16x2(v.x, v.y);
    p.y = pack_bf16x2(v.z, v.w);
    ((uint2*)x)[i] = p;
}

// ---------------------------------------------------------------------------
// CSR build: histogram of edge rows
// ---------------------------------------------------------------------------
__global__ void k_hist(const int* __restrict__ row, int* __restrict__ counts) {
    int e = blockIdx.x * blockDim.x + threadIdx.x;
    if (e < N_EDGES) atomicAdd(&counts[row[e]], 1);
}

// ---------------------------------------------------------------------------
// 3-kernel exclusive scan (same as round 1)
// ---------------------------------------------------------------------------
__global__ void k_scan1(const int* __restrict__ counts,
                        int* __restrict__ scanned,
                        int* __restrict__ part) {
    __shared__ int lds[256];
    int tid  = threadIdx.x;
    int base = blockIdx.x * SCAN_CHUNK + tid * 4;
    int v0 = (base + 0 < N_NODES) ? counts[base + 0] : 0;
    int v1 = (base + 1 < N_NODES) ? counts[base + 1] : 0;
    int v2 = (base + 2 < N_NODES) ? counts[base + 2] : 0;
    int v3 = (base + 3 < N_NODES) ? counts[base + 3] : 0;
    int tsum = v0 + v1 + v2 + v3;
    lds[tid] = tsum;
    __syncthreads();
    for (int off = 1; off < 256; off <<= 1) {
        int t = (tid >= off) ? lds[tid - off] : 0;
        __syncthreads();
        lds[tid] += t;
        __syncthreads();
    }
    if (tid == 255) part[blockIdx.x] = lds[255];
    int run = lds[tid] - tsum;   // exclusive
    if (base + 0 < N_NODES) scanned[base + 0] = run; run += v0;
    if (base + 1 < N_NODES) scanned[base + 1] = run; run += v1;
    if (base + 2 < N_NODES) scanned[base + 2] = run; run += v2;
    if (base + 3 < N_NODES) scanned[base + 3] = run;
}

__global__ void k_scan2(int* __restrict__ part, int* __restrict__ scanned) {
    __shared__ int lds[256];
    int tid = threadIdx.x;
    int v = (tid < SCAN_BLOCKS) ? part[tid] : 0;
    lds[tid] = v;
    __syncthreads();
    for (int off = 1; off < 256; off <<= 1) {
        int t = (tid >= off) ? lds[tid - off] : 0;
        __syncthreads();
        lds[tid] += t;
        __syncthreads();
    }
    if (tid < SCAN_BLOCKS) part[tid] = lds[tid] - v;  // exclusive
    if (tid == 0) scanned[N_NODES] = N_EDGES;
}

__global__ void k_scan3(int* __restrict__ scanned,
                        const int* __restrict__ part,
                        int* __restrict__ cursor) {
    int off  = part[blockIdx.x];
    int base = blockIdx.x * SCAN_CHUNK + threadIdx.x * 4;
    #pragma unroll
    for (int j = 0; j < 4; ++j) {
        int i = base + j;
        if (i < N_NODES) {
            int v = scanned[i] + off;
            scanned[i] = v;
            cursor[i]  = v;
        }
    }
}

// ---------------------------------------------------------------------------
// CSR fill: edges[pos] = {col, w}, pos via per-row atomic cursor
// ---------------------------------------------------------------------------
__global__ void k_fill(const int* __restrict__ row, const int* __restrict__ col,
                       const float* __restrict__ w,
                       int* __restrict__ cursor, int2* __restrict__ edges) {
    int e = blockIdx.x * blockDim.x + threadIdx.x;
    if (e >= N_EDGES) return;
    int pos = atomicAdd(&cursor[row[e]], 1);
    int2 v;
    v.x = col[e];
    v.y = __float_as_int(w[e]);
    edges[pos] = v;
}

// ---------------------------------------------------------------------------
// Gather SpMM over bf16 tables: one 32-lane group per node, lane owns 2 dims
// (one packed u32). f32 accumulate, bf16 store.
// ---------------------------------------------------------------------------
__global__ void k_spmm_bf16(const int* __restrict__ row_start,
                            const int2* __restrict__ edges,
                            const unsigned* __restrict__ xin,
                            unsigned* __restrict__ xout) {
    int g = blockIdx.x * (blockDim.x >> 5) + (threadIdx.x >> 5);  // node
    int l = threadIdx.x & 31;                                      // dims [2l,2l+1]
    if (g >= N_NODES) return;
    int s = row_start[g];
    int e = row_start[g + 1];
    float ax0 = 0.f, ay0 = 0.f, ax1 = 0.f, ay1 = 0.f;
    int i = s;
    for (; i + 1 < e; i += 2) {
        int2 e0 = edges[i];
        int2 e1 = edges[i + 1];
        float w0 = __int_as_float(e0.y);
        float w1 = __int_as_float(e1.y);
        float2 v0 = unpack_bf16x2(xin[(size_t)e0.x * 32 + l]);
        float2 v1 = unpack_bf16x2(xin[(size_t)e1.x * 32 + l]);
        ax0 += w0 * v0.x; ay0 += w0 * v0.y;
        ax1 += w1 * v1.x; ay1 += w1 * v1.y;
    }
    if (i < e) {
        int2 e0 = edges[i];
        float w0 = __int_as_float(e0.y);
        float2 v0 = unpack_bf16x2(xin[(size_t)e0.x * 32 + l]);
        ax0 += w0 * v0.x; ay0 += w0 * v0.y;
    }
    xout[(size_t)g * 32 + l] = pack_bf16x2(ax0 + ax1, ay0 + ay1);
}

// ---------------------------------------------------------------------------
// out[g] = 0.25*(ego_f32[node] + x1[node] + x2[node])   (full write, no memset)
// ---------------------------------------------------------------------------
__global__ void k_gather_base(const int* __restrict__ users,
                              const int* __restrict__ items,
                              const float* __restrict__ ue,
                              const float* __restrict__ ie,
                              const unsigned* __restrict__ x1,
                              const unsigned* __restrict__ x2,
                              float* __restrict__ out) {
    int g = blockIdx.x * (blockDim.x >> 5) + (threadIdx.x >> 5);
    int l = threadIdx.x & 31;
    if (g >= 2 * BATCH) return;
    int node = (g < BATCH) ? users[g] : USER_COUNT + items[g - BATCH];
    const float* ego = (node < USER_COUNT)
                         ? ue + (size_t)node * EMB
                         : ie + (size_t)(node - USER_COUNT) * EMB;
    float2 e = ((const float2*)ego)[l];
    float2 a = unpack_bf16x2(x1[(size_t)node * 32 + l]);
    float2 b = unpack_bf16x2(x2[(size_t)node * 32 + l]);
    float2 r;
    r.x = 0.25f * (e.x + a.x + b.x);
    r.y = 0.25f * (e.y + a.y + b.y);
    ((float2*)out)[(size_t)g * 32 + l] = r;
}

// ---------------------------------------------------------------------------
// Layer-3 SpMM computed ONLY at the 8192 selected nodes, fused into out +=
// ---------------------------------------------------------------------------
__global__ void k_out_spmm(const int* __restrict__ users,
                           const int* __restrict__ items,
                           const int* __restrict__ row_start,
                           const int2* __restrict__ edges,
                           const unsigned* __restrict__ xin,
                           float* __restrict__ out) {
    int g = blockIdx.x * (blockDim.x >> 5) + (threadIdx.x >> 5);
    int l = threadIdx.x & 31;
    if (g >= 2 * BATCH) return;
    int node = (g < BATCH) ? users[g] : USER_COUNT + items[g - BATCH];
    int s = row_start[node];
    int e = row_start[node + 1];
    float ax0 = 0.f, ay0 = 0.f, ax1 = 0.f, ay1 = 0.f;
    int i = s;
    for (; i + 1 < e; i += 2) {
        int2 e0 = edges[i];
        int2 e1 = edges[i + 1];
        float w0 = __int_as_float(e0.y);
        float w1 = __int_as_float(e1.y);
        float2 v0 = unpack_bf16x2(xin[(size_t)e0.x * 32 + l]);
        float2 v1 = unpack_bf16x2(xin[(size_t)e1.x * 32 + l]);
        ax0 += w0 * v0.x; ay0 += w0 * v0.y;
        ax1 += w1 * v1.x; ay1 += w1 * v1.y;
    }
    if (i < e) {
        int2 e0 = edges[i];
        float w0 = __int_as_float(e0.y);
        float2 v0 = unpack_bf16x2(xin[(size_t)e0.x * 32 + l]);
        ax0 += w0 * v0.x; ay0 += w0 * v0.y;
    }
    float2* o = (float2*)out + (size_t)g * 32 + l;
    float2 cur = *o;
    cur.x += 0.25f * (ax0 + ax1);
    cur.y += 0.25f * (ay0 + ay1);
    *o = cur;
}

extern "C" void kernel_launch(void* const* d_in, const int* in_sizes, int n_in,
                              void* d_out, int out_size, void* d_ws, size_t ws_size,
                              hipStream_t stream) {
    const float* user_emb    = (const float*)d_in[0];
    const float* item_emb    = (const float*)d_in[1];
    const int*   edge_row    = (const int*)d_in[2];
    const int*   edge_col    = (const int*)d_in[3];
    const float* edge_weight = (const float*)d_in[4];
    const int*   users       = (const int*)d_in[5];
    const int*   items       = (const int*)d_in[6];
    float* out = (float*)d_out;

    // ws layout (bf16 tables are N_NODES*32 u32 = 19.2 MB each)
    const size_t node_u32 = (size_t)N_NODES * 32;
    unsigned* xa        = (unsigned*)d_ws;            // ego (bf16)
    unsigned* xb        = xa + node_u32;              // x1
    unsigned* xc        = xb + node_u32;              // x2
    int*      row_start = (int*)(xc + node_u32);      // NPAD ints (uses N_NODES+1)
    int*      cursor    = row_start + NPAD;
    int*      counts    = cursor + NPAD;
    int*      part      = counts + NPAD;              // 256 ints
    int2*     edges     = (int2*)(part + 256);        // 10 MB

    // x0 = ego -> bf16 table
    {
        size_t n4 = (size_t)N_NODES * EMB / 4;
        int blocks = (int)((n4 + 255) / 256);
        k_concat_bf16<<<blocks, 256, 0, stream>>>(user_emb, item_emb, xa);
    }

    // ---------- CSR build ----------
    hipMemsetAsync(counts, 0, (size_t)NPAD * sizeof(int), stream);
    {
        int blocks = (N_EDGES + 255) / 256;
        k_hist<<<blocks, 256, 0, stream>>>(edge_row, counts);
    }
    k_scan1<<<SCAN_BLOCKS, 256, 0, stream>>>(counts, row_start, part);
    k_scan2<<<1, 256, 0, stream>>>(part, row_start);
    k_scan3<<<SCAN_BLOCKS, 256, 0, stream>>>(row_start, part, cursor);
    {
        int blocks = (N_EDGES + 255) / 256;
        k_fill<<<blocks, 256, 0, stream>>>(edge_row, edge_col, edge_weight,
                                           cursor, edges);
    }

    // ---------- layers 1,2 full SpMM (bf16) ----------
    const int spmm_blocks = (N_NODES + 7) / 8;        // 8 nodes per 256-thr block
    k_spmm_bf16<<<spmm_blocks, 256, 0, stream>>>(row_start, edges, xa, xb);
    k_spmm_bf16<<<spmm_blocks, 256, 0, stream>>>(row_start, edges, xb, xc);

    // ---------- epilogue: out = 0.25*(ego+x1+x2), then += 0.25*layer3 ----------
    const int ep_blocks = (2 * BATCH + 7) / 8;
    k_gather_base<<<ep_blocks, 256, 0, stream>>>(users, items, user_emb, item_emb,
                                                 xb, xc, out);
    k_out_spmm<<<ep_blocks, 256, 0, stream>>>(users, items, row_start, edges,
                                              xc, out);
}

// Round 5
// 196.291 us; speedup vs baseline: 16.3840x; 1.3946x over previous
//
#include <hip/hip_runtime.h>

#define USER_COUNT 100000
#define ITEM_COUNT 50000
#define N_NODES    150000   // USER_COUNT + ITEM_COUNT
#define EMB        64
#define N_EDGES    1250000
#define BATCH      4096

#define NBKT      147                 // ceil(150000 / 1024), bucket = row >> 10
#define BROWS     1024                // rows per bucket
#define A1_TILE   2048
#define A1_BLOCKS ((N_EDGES + A1_TILE - 1) / A1_TILE)   // 611
#define COLMASK   0x3FFFFu
#define ROW_ALLOC 150536              // >= NBKT*BROWS (150528), 16B padded

// bf16x2 pack/unpack (round-to-nearest-even; inputs are finite)
static __device__ __forceinline__ unsigned pack_bf16x2(float a, float b) {
    unsigned ua = __float_as_uint(a);
    unsigned ub = __float_as_uint(b);
    ua += 0x7FFFu + ((ua >> 16) & 1u);
    ub += 0x7FFFu + ((ub >> 16) & 1u);
    return (ua >> 16) | (ub & 0xFFFF0000u);
}
static __device__ __forceinline__ float2 unpack_bf16x2(unsigned v) {
    float2 r;
    r.x = __uint_as_float(v << 16);
    r.y = __uint_as_float(v & 0xFFFF0000u);
    return r;
}

// ---------------------------------------------------------------------------
// x0 = concat(user_emb, item_emb) -> bf16x2-packed table
// ---------------------------------------------------------------------------
__global__ void k_concat_bf16(const float* __restrict__ ue,
                              const float* __restrict__ ie,
                              unsigned* __restrict__ x) {
    const size_t nu4 = (size_t)USER_COUNT * EMB / 4;
    const size_t nt4 = (size_t)N_NODES   * EMB / 4;
    size_t i = (size_t)blockIdx.x * blockDim.x + threadIdx.x;
    if (i >= nt4) return;
    float4 v = (i < nu4) ? ((const float4*)ue)[i] : ((const float4*)ie)[i - nu4];
    uint2 p;
    p.x = pack_bf16x2(v.x, v.y);
    p.y = pack_bf16x2(v.z, v.w);
    ((uint2*)x)[i] = p;
}

// ---------------------------------------------------------------------------
// Bucket histogram (147 buckets), LDS-staged
// ---------------------------------------------------------------------------
__global__ void k_bhist(const int* __restrict__ row, int* __restrict__ gcount) {
    __shared__ int h[NBKT];
    int tid = threadIdx.x;
    if (tid < NBKT) h[tid] = 0;
    __syncthreads();
    int base = blockIdx.x * 1024;
    #pragma unroll
    for (int j = 0; j < 4; ++j) {
        int e = base + j * 256 + tid;
        if (e < N_EDGES) atomicAdd(&h[row[e] >> 10], 1);
    }
    __syncthreads();
    if (tid < NBKT && h[tid]) atomicAdd(&gcount[tid], h[tid]);
}

// ---------------------------------------------------------------------------
// Scan of 147 bucket counts -> gstart (exclusive) and gcursor copy.
// BUGFIX (round 4): only threads 0..NBKT may write — tid 160..255 previously
// overflowed gstart[160] into gcursor[0..] (racy cursor corruption).
// ---------------------------------------------------------------------------
__global__ void k_bscan(const int* __restrict__ gcount,
                        int* __restrict__ gstart, int* __restrict__ gcursor) {
    __shared__ int sA[256], sB[256];
    int tid = threadIdx.x;
    int v = (tid < NBKT) ? gcount[tid] : 0;
    sA[tid] = v;
    __syncthreads();
    int* in = sA; int* out = sB;
    for (int off = 1; off < 256; off <<= 1) {
        out[tid] = in[tid] + ((tid >= off) ? in[tid - off] : 0);
        __syncthreads();
        int* t = in; in = out; out = t;
    }
    int excl = in[tid] - v;       // tid == NBKT: == N_EDGES (sentinel)
    if (tid <= NBKT) {
        gstart[tid]  = excl;
        gcursor[tid] = excl;
    }
}

// ---------------------------------------------------------------------------
// Pass A1: bucket-sort edges into edges_a with coherent (staged) writes.
// Each block: 2048 edges -> LDS hist -> scan -> LDS scatter -> ordered flush.
// Record: {col | (row&1023)<<18, w_f32}
// ---------------------------------------------------------------------------
__global__ void k_binfill(const int* __restrict__ row, const int* __restrict__ col,
                          const float* __restrict__ w,
                          int* __restrict__ gcursor, uint2* __restrict__ edges_a) {
    __shared__ int cnt[256], cnt2[NBKT], gpos[NBKT], sc[NBKT];
    __shared__ int sA[256], sB[256];
    __shared__ uint2 srec[A1_TILE];
    __shared__ int  sdst[A1_TILE];
    int tid = threadIdx.x;
    cnt[tid] = 0;
    if (tid < NBKT) cnt2[tid] = 0;
    __syncthreads();

    int ebase   = blockIdx.x * A1_TILE;
    int tilecnt = min(A1_TILE, N_EDGES - ebase);

    int r[8], c[8]; float wv[8];
    #pragma unroll
    for (int j = 0; j < 8; ++j) {
        int e = ebase + j * 256 + tid;
        if (e < N_EDGES) {
            r[j] = row[e]; c[j] = col[e]; wv[j] = w[e];
            atomicAdd(&cnt[r[j] >> 10], 1);
        } else {
            r[j] = -1;
        }
    }
    __syncthreads();

    // exclusive scan of cnt over 256 slots
    int* in = sA; int* out = sB;
    in[tid] = cnt[tid];
    __syncthreads();
    for (int off = 1; off < 256; off <<= 1) {
        out[tid] = in[tid] + ((tid >= off) ? in[tid - off] : 0);
        __syncthreads();
        int* t = in; in = out; out = t;
    }
    if (tid < NBKT) {
        sc[tid]   = in[tid] - cnt[tid];
        gpos[tid] = atomicAdd(&gcursor[tid], cnt[tid]);
    }
    __syncthreads();

    // scatter into LDS staging in bucket order, remember global destination
    #pragma unroll
    for (int j = 0; j < 8; ++j) {
        if (r[j] >= 0) {
            int b  = r[j] >> 10;
            int lp = sc[b] + atomicAdd(&cnt2[b], 1);
            srec[lp] = make_uint2((unsigned)c[j] | ((unsigned)(r[j] & 1023) << 18),
                                  __float_as_uint(wv[j]));
            sdst[lp] = gpos[b] + (lp - sc[b]);
        }
    }
    __syncthreads();

    // flush in staged (bucket-sorted) order -> contiguous runs per bucket
    #pragma unroll
    for (int j = 0; j < 8; ++j) {
        int i = j * 256 + tid;
        if (i < tilecnt) edges_a[sdst[i]] = srec[i];
    }
}

// ---------------------------------------------------------------------------
// Pass A2: per-bucket exact CSR. One block per bucket; per-row hist/scan in
// LDS; writes row_start and the final per-row-sorted edges_b (block-local
// 68 KB destination region -> no cross-XCD false sharing).
// ---------------------------------------------------------------------------
__global__ __launch_bounds__(512) void k_csrfill(const int* __restrict__ gstart,
                                                 const uint2* __restrict__ edges_a,
                                                 uint2* __restrict__ edges_b,
                                                 int* __restrict__ row_start) {
    __shared__ int hist[BROWS], cur[BROWS];
    __shared__ int sA[BROWS], sB[BROWS];
    int tid   = threadIdx.x;
    int b     = blockIdx.x;
    int base  = gstart[b];
    int count = gstart[b + 1] - base;

    hist[tid] = 0; hist[tid + 512] = 0;
    __syncthreads();
    for (int i = tid; i < count; i += 512) {
        unsigned a = edges_a[base + i].x;
        atomicAdd(&hist[(a >> 18) & 1023], 1);
    }
    __syncthreads();

    // scan 1024 with 512 threads (Hillis-Steele, ping-pong)
    int* in = sA; int* out = sB;
    in[tid] = hist[tid]; in[tid + 512] = hist[tid + 512];
    __syncthreads();
    for (int off = 1; off < 1024; off <<= 1) {
        out[tid] = in[tid] + ((tid >= off) ? in[tid - off] : 0);
        int i2 = tid + 512;
        out[i2] = in[i2] + ((i2 >= off) ? in[i2 - off] : 0);
        __syncthreads();
        int* t = in; in = out; out = t;
    }
    #pragma unroll
    for (int k = 0; k < 2; ++k) {
        int rl   = tid + k * 512;
        int excl = in[rl] - hist[rl];
        row_start[b * BROWS + rl] = base + excl;
        cur[rl] = base + excl;
    }
    __syncthreads();

    for (int i = tid; i < count; i += 512) {
        uint2 rec = edges_a[base + i];
        int rl  = (rec.x >> 18) & 1023;
        int pos = atomicAdd(&cur[rl], 1);
        edges_b[pos] = rec;
    }
}

// ---------------------------------------------------------------------------
// Mark nodes whose x2 is needed: the selected nodes + cols of their edges
// ---------------------------------------------------------------------------
__global__ void k_mark(const int* __restrict__ users, const int* __restrict__ items,
                       const int* __restrict__ row_start,
                       const uint2* __restrict__ edges_b,
                       unsigned char* __restrict__ flag) {
    int t = blockIdx.x * blockDim.x + threadIdx.x;
    int g = t >> 3;
    int l = t & 7;
    if (g >= 2 * BATCH) return;
    int node = (g < BATCH) ? users[g] : USER_COUNT + items[g - BATCH];
    if (l == 0) flag[node] = 1;
    int s = row_start[node], e = row_start[node + 1];
    for (int i = s + l; i < e; i += 8)
        flag[edges_b[i].x & COLMASK] = 1;
}

// ---------------------------------------------------------------------------
// Gather SpMM over bf16 tables: 32-lane group per node, lane owns 2 dims.
// Optional row pruning via flag (nullptr = compute all rows).
// ---------------------------------------------------------------------------
__global__ void k_spmm_bf16(const int* __restrict__ row_start,
                            const uint2* __restrict__ edges,
                            const unsigned* __restrict__ xin,
                            unsigned* __restrict__ xout,
                            const unsigned char* __restrict__ flag) {
    int g = blockIdx.x * (blockDim.x >> 5) + (threadIdx.x >> 5);
    int l = threadIdx.x & 31;
    if (g >= N_NODES) return;
    if (flag && !flag[g]) return;
    int s = row_start[g];
    int e = row_start[g + 1];
    float ax0 = 0.f, ay0 = 0.f, ax1 = 0.f, ay1 = 0.f;
    int i = s;
    for (; i + 1 < e; i += 2) {
        uint2 e0 = edges[i];
        uint2 e1 = edges[i + 1];
        float w0 = __uint_as_float(e0.y);
        float w1 = __uint_as_float(e1.y);
        float2 v0 = unpack_bf16x2(xin[(size_t)(e0.x & COLMASK) * 32 + l]);
        float2 v1 = unpack_bf16x2(xin[(size_t)(e1.x & COLMASK) * 32 + l]);
        ax0 += w0 * v0.x; ay0 += w0 * v0.y;
        ax1 += w1 * v1.x; ay1 += w1 * v1.y;
    }
    if (i < e) {
        uint2 e0 = edges[i];
        float w0 = __uint_as_float(e0.y);
        float2 v0 = unpack_bf16x2(xin[(size_t)(e0.x & COLMASK) * 32 + l]);
        ax0 += w0 * v0.x; ay0 += w0 * v0.y;
    }
    xout[(size_t)g * 32 + l] = pack_bf16x2(ax0 + ax1, ay0 + ay1);
}

// ---------------------------------------------------------------------------
// out[g] = 0.25*(ego_f32[node] + x1[node] + x2[node])
// ---------------------------------------------------------------------------
__global__ void k_gather_base(const int* __restrict__ users,
                              const int* __restrict__ items,
                              const float* __restrict__ ue,
                              const float* __restrict__ ie,
                              const unsigned* __restrict__ x1,
                              const unsigned* __restrict__ x2,
                              float* __restrict__ out) {
    int g = blockIdx.x * (blockDim.x >> 5) + (threadIdx.x >> 5);
    int l = threadIdx.x & 31;
    if (g >= 2 * BATCH) return;
    int node = (g < BATCH) ? users[g] : USER_COUNT + items[g - BATCH];
    const float* ego = (node < USER_COUNT)
                         ? ue + (size_t)node * EMB
                         : ie + (size_t)(node - USER_COUNT) * EMB;
    float2 e = ((const float2*)ego)[l];
    float2 a = unpack_bf16x2(x1[(size_t)node * 32 + l]);
    float2 b = unpack_bf16x2(x2[(size_t)node * 32 + l]);
    float2 r;
    r.x = 0.25f * (e.x + a.x + b.x);
    r.y = 0.25f * (e.y + a.y + b.y);
    ((float2*)out)[(size_t)g * 32 + l] = r;
}

// ---------------------------------------------------------------------------
// Layer-3 SpMM only at the 8192 selected nodes, fused into out +=
// ---------------------------------------------------------------------------
__global__ void k_out_spmm(const int* __restrict__ users,
                           const int* __restrict__ items,
                           const int* __restrict__ row_start,
                           const uint2* __restrict__ edges,
                           const unsigned* __restrict__ xin,
                           float* __restrict__ out) {
    int g = blockIdx.x * (blockDim.x >> 5) + (threadIdx.x >> 5);
    int l = threadIdx.x & 31;
    if (g >= 2 * BATCH) return;
    int node = (g < BATCH) ? users[g] : USER_COUNT + items[g - BATCH];
    int s = row_start[node];
    int e = row_start[node + 1];
    float ax0 = 0.f, ay0 = 0.f, ax1 = 0.f, ay1 = 0.f;
    int i = s;
    for (; i + 1 < e; i += 2) {
        uint2 e0 = edges[i];
        uint2 e1 = edges[i + 1];
        float w0 = __uint_as_float(e0.y);
        float w1 = __uint_as_float(e1.y);
        float2 v0 = unpack_bf16x2(xin[(size_t)(e0.x & COLMASK) * 32 + l]);
        float2 v1 = unpack_bf16x2(xin[(size_t)(e1.x & COLMASK) * 32 + l]);
        ax0 += w0 * v0.x; ay0 += w0 * v0.y;
        ax1 += w1 * v1.x; ay1 += w1 * v1.y;
    }
    if (i < e) {
        uint2 e0 = edges[i];
        float w0 = __uint_as_float(e0.y);
        float2 v0 = unpack_bf16x2(xin[(size_t)(e0.x & COLMASK) * 32 + l]);
        ax0 += w0 * v0.x; ay0 += w0 * v0.y;
    }
    float2* o = (float2*)out + (size_t)g * 32 + l;
    float2 cur = *o;
    cur.x += 0.25f * (ax0 + ax1);
    cur.y += 0.25f * (ay0 + ay1);
    *o = cur;
}

extern "C" void kernel_launch(void* const* d_in, const int* in_sizes, int n_in,
                              void* d_out, int out_size, void* d_ws, size_t ws_size,
                              hipStream_t stream) {
    const float* user_emb    = (const float*)d_in[0];
    const float* item_emb    = (const float*)d_in[1];
    const int*   edge_row    = (const int*)d_in[2];
    const int*   edge_col    = (const int*)d_in[3];
    const float* edge_weight = (const float*)d_in[4];
    const int*   users       = (const int*)d_in[5];
    const int*   items       = (const int*)d_in[6];
    float* out = (float*)d_out;

    // ws layout (small arrays padded to 256 ints each)
    const size_t node_u32 = (size_t)N_NODES * 32;     // 19.2 MB per table
    unsigned* xa        = (unsigned*)d_ws;            // ego (bf16)
    unsigned* xb        = xa + node_u32;              // x1
    unsigned* xc        = xb + node_u32;              // x2 (pruned rows only)
    int*      row_start = (int*)(xc + node_u32);      // ROW_ALLOC ints
    int*      gcount    = row_start + ROW_ALLOC;      // 256
    int*      gstart    = gcount + 256;               // 256
    int*      gcursor   = gstart + 256;               // 256
    unsigned char* flag = (unsigned char*)(gcursor + 256);   // 150528 bytes
    uint2*    edges_a   = (uint2*)(flag + 150528);    // 10 MB
    uint2*    edges_b   = edges_a + N_EDGES;          // 10 MB
    // total ~78.4 MB

    // x0 -> bf16 table
    {
        size_t n4 = (size_t)N_NODES * EMB / 4;
        int blocks = (int)((n4 + 255) / 256);
        k_concat_bf16<<<blocks, 256, 0, stream>>>(user_emb, item_emb, xa);
    }

    // ---------- CSR build (write-coherent, 2-level) ----------
    hipMemsetAsync(gcount, 0, 256 * sizeof(int), stream);
    hipMemsetAsync(flag, 0, 150528, stream);
    {
        int blocks = (N_EDGES + 1023) / 1024;
        k_bhist<<<blocks, 256, 0, stream>>>(edge_row, gcount);
    }
    k_bscan<<<1, 256, 0, stream>>>(gcount, gstart, gcursor);
    k_binfill<<<A1_BLOCKS, 256, 0, stream>>>(edge_row, edge_col, edge_weight,
                                             gcursor, edges_a);
    k_csrfill<<<NBKT, 512, 0, stream>>>(gstart, edges_a, edges_b, row_start);

    // ---------- layers ----------
    const int spmm_blocks = (N_NODES + 7) / 8;
    k_spmm_bf16<<<spmm_blocks, 256, 0, stream>>>(row_start, edges_b, xa, xb,
                                                 (const unsigned char*)nullptr);
    k_mark<<<(2 * BATCH * 8 + 255) / 256, 256, 0, stream>>>(users, items, row_start,
                                                            edges_b, flag);
    k_spmm_bf16<<<spmm_blocks, 256, 0, stream>>>(row_start, edges_b, xb, xc, flag);

    // ---------- epilogue ----------
    const int ep_blocks = (2 * BATCH + 7) / 8;
    k_gather_base<<<ep_blocks, 256, 0, stream>>>(users, items, user_emb, item_emb,
                                                 xb, xc, out);
    k_out_spmm<<<ep_blocks, 256, 0, stream>>>(users, items, row_start, edges_b,
                                              xc, out);
}